// Round 6
// baseline (200.553 us; speedup 1.0000x reference)
//
#include <hip/hip_runtime.h>

#define LRC   0.01f
#define WCLIP 5.0f
#define LO   (-4.5951198501345898f)
#define HI   ( 4.5951198501345898f)
#define PDSZ (4096 * 256)

__device__ __forceinline__ unsigned short f2bf(float f) {
    unsigned int u = __float_as_uint(f);
    u += 0x7fffu + ((u >> 16) & 1u);          // RNE
    return (unsigned short)(u >> 16);
}
__device__ __forceinline__ float bflo(unsigned int p) { return __uint_as_float(p << 16); }
__device__ __forceinline__ float bfhi(unsigned int p) { return __uint_as_float(p & 0xffff0000u); }

// ---------------------------------------------------------------------------
// K1: distances GEMM, FMA-dense tiles. Blocks 0..511: 128(m)x64(n) tile,
//     8x4 per thread (3 b128 LDS reads per 32 FMAs -> FMA-bound, vs 2 per 16
//     for the old 4x4), K-split 4 (K=128/block, BK=32), register prefetch.
//     Ascending-k fp32 chains identical to R5 -> pd bitwise-stable.
//     Blocks 512..575: logits transpose -> lT. Block 576: colb = -1 init.
// ---------------------------------------------------------------------------
__global__ __launch_bounds__(256) void k1_part(
    const float* __restrict__ cmap,    // (4096, 512)
    const float* __restrict__ ctx,     // (512, 256)
    const float* __restrict__ logits,  // (1024, 256)
    float* __restrict__ pd,            // 4 x (4096, 256) partials
    float* __restrict__ lT,            // (256, 1024)
    int*   __restrict__ colb)          // (16384) winner columns
{
    __shared__ __align__(16) float As[64 * 68];   // GEMM: As[k][m] stride 132 (4224 f); transpose: T[64][68]
    __shared__ __align__(16) float Bs[32 * 68];   // Bs[k][n] stride 68
    const int t   = threadIdx.x;
    const int blk = blockIdx.x;

    if (blk < 512) {
        const int kq = blk & 3;
        const int tN = (blk >> 2) & 3;
        const int tM = blk >> 4;
        const int m0 = tM << 7, n0 = tN << 6, kbase = kq << 7;
        const int tm = t >> 4, tn = t & 15;

        // staging geometry
        const int ar = t >> 3;             // + rep*32  (A m-row)
        const int ac = (t & 7) << 2;       // A k-col (4-wide)
        const int br = t >> 4;             // + rep*16  (B k-row)
        const int bc = (t & 15) << 2;      // B n-col (4-wide)

        float acc[8][4];
        #pragma unroll
        for (int i = 0; i < 8; i++)
            #pragma unroll
            for (int j = 0; j < 4; j++) acc[i][j] = 0.f;

        float4 va[4], vb[2];
        #pragma unroll
        for (int rep = 0; rep < 4; rep++)
            va[rep] = *(const float4*)(cmap + (m0 + (rep << 5) + ar) * 512 + kbase + ac);
        #pragma unroll
        for (int rep = 0; rep < 2; rep++)
            vb[rep] = *(const float4*)(ctx + (kbase + (rep << 4) + br) * 256 + n0 + bc);

        for (int kt = 0; kt < 4; ++kt) {
            const int k0 = kbase + (kt << 5);
            __syncthreads();
            #pragma unroll
            for (int rep = 0; rep < 4; rep++) {
                const int r = (rep << 5) + ar;
                As[(ac + 0) * 132 + r] = va[rep].x;      // A transposed: As[k][m]
                As[(ac + 1) * 132 + r] = va[rep].y;
                As[(ac + 2) * 132 + r] = va[rep].z;
                As[(ac + 3) * 132 + r] = va[rep].w;
            }
            #pragma unroll
            for (int rep = 0; rep < 2; rep++)
                *(float4*)(Bs + ((rep << 4) + br) * 68 + bc) = vb[rep];
            if (kt < 3) {                                // next tile in flight
                #pragma unroll
                for (int rep = 0; rep < 4; rep++)
                    va[rep] = *(const float4*)(cmap + (m0 + (rep << 5) + ar) * 512 + k0 + 32 + ac);
                #pragma unroll
                for (int rep = 0; rep < 2; rep++)
                    vb[rep] = *(const float4*)(ctx + (k0 + 32 + (rep << 4) + br) * 256 + n0 + bc);
            }
            __syncthreads();

            const float* ap = As + (tm << 3);
            const float* bp = Bs + (tn << 2);
            #pragma unroll 4
            for (int k = 0; k < 32; ++k) {
                float4 a0 = *(const float4*)(ap + k * 132);
                float4 a1 = *(const float4*)(ap + k * 132 + 4);
                float4 b4 = *(const float4*)(bp + k * 68);
                const float am[8] = {a0.x, a0.y, a0.z, a0.w, a1.x, a1.y, a1.z, a1.w};
                #pragma unroll
                for (int i = 0; i < 8; i++) {
                    acc[i][0] = fmaf(am[i], b4.x, acc[i][0]);
                    acc[i][1] = fmaf(am[i], b4.y, acc[i][1]);
                    acc[i][2] = fmaf(am[i], b4.z, acc[i][2]);
                    acc[i][3] = fmaf(am[i], b4.w, acc[i][3]);
                }
            }
        }
        float* dst = pd + (long)kq * PDSZ;
        #pragma unroll
        for (int i = 0; i < 8; i++) {
            float4 v = make_float4(acc[i][0], acc[i][1], acc[i][2], acc[i][3]);
            *(float4*)(dst + (m0 + (tm << 3) + i) * 256 + n0 + (tn << 2)) = v;
        }
    } else if (blk < 576) {
        // transpose one 64(i) x 64(b) tile of logits into lT
        float* T = As;
        const int bi = blk - 512;
        const int i0 = (bi >> 2) << 6;
        const int b0 = (bi & 3) << 6;
        #pragma unroll
        for (int rep = 0; rep < 4; rep++) {
            int flat4 = rep * 256 + t;
            int r = flat4 >> 4;                       // i-local
            int c = (flat4 & 15) << 2;                // b-local
            float4 v = *(const float4*)(logits + (i0 + r) * 256 + b0 + c);
            T[(c + 0) * 68 + r] = v.x;
            T[(c + 1) * 68 + r] = v.y;
            T[(c + 2) * 68 + r] = v.z;
            T[(c + 3) * 68 + r] = v.w;
        }
        __syncthreads();
        #pragma unroll
        for (int rep = 0; rep < 4; rep++) {
            int flat4 = rep * 256 + t;
            int r = flat4 >> 4;                       // b-local
            int c = (flat4 & 15) << 2;                // i-local
            *(float4*)(lT + (b0 + r) * 1024 + i0 + c) =
                *(const float4*)(T + r * 68 + c);
        }
    } else {
        for (int k = t; k < 16384; k += 256) colb[k] = -1;
    }
}

// ---------------------------------------------------------------------------
// K2a: idx (from pd) + forward dots + global last-b argmax.
//      512 blocks x 1024 thr: 4 neurons x 128 cols (b-split x2 -> 2 blocks/CU,
//      32 waves: latency overlap that 256-block rounds never had). Weights
//      staged bf16 (exact for 1/1024) in two 512-i mega-chunks, XOR-swizzled.
//      Winner column -> global atomicMax(colb); coef computed in k2b.
// ---------------------------------------------------------------------------
__global__ __launch_bounds__(1024, 4) void k2a_fwd(
    const float* __restrict__ logits,   // (1024, 256)
    const float* __restrict__ weights,  // (1024, 16, 1024)
    const float* __restrict__ bias,     // (1)
    const float* __restrict__ cbias,    // (4096)
    const float* __restrict__ pd,       // 4 x (4096, 256)
    float* __restrict__ outp,           // d_out first 1024*256
    int*   __restrict__ colb)           // (16384), pre-init -1
{
    __shared__ __align__(16) unsigned short wlds[64 * 512];   // 64 KB
    __shared__ int idx_lds[512];                              // [g][128]
    float* red = (float*)wlds;    // alias, valid after final gather barrier

    const int t  = threadIdx.x;
    const int bl = t & 127;               // block-local column
    const int q  = t >> 7;                // i-octant 0..7 (64 i per chunk)
    const int bh = blockIdx.x & 1;
    const int s0 = (blockIdx.x >> 1) << 2;
    const int bc = (bh << 7) + bl;        // global column

    // ---- idx for this block's 128 columns (t<128), + global argmax ----
    if (t < 128) {
        #pragma unroll
        for (int g = 0; g < 4; g++) {
            int v = 0;
            #pragma unroll
            for (int mm = 0; mm < 4; mm++) {
                const float* pp = pd + ((s0 + g) * 4 + mm) * 256 + (bh << 7) + t;
                float d = ((pp[0] + pp[PDSZ]) + pp[2 * PDSZ]) + pp[3 * PDSZ];
                v |= (d > cbias[(s0 + g) * 4 + mm]) ? (1 << mm) : 0;
            }
            idx_lds[(g << 7) + t] = v;
            atomicMax(&colb[((s0 + g) << 4) + v], (bh << 7) + t);
        }
    }

    // ---- staging geometry: thread covers (row r, cols c+seg*64) ----
    const int r  = t >> 4;                // 0..63 = g*16 + j
    const int c  = (t & 15) << 2;         // 0..60
    const float* wsrc = weights + ((s0 + (r >> 4)) << 14) + ((r & 15) << 10) + c;
    const int swz     = (r & 15) << 3;    // swizzle = 8*j
    const int ldsbase = r << 9;           // r*512

    // ---- chunk 0 global loads + LDS write ----
    float4 pf[8];
    #pragma unroll
    for (int seg = 0; seg < 8; ++seg)
        pf[seg] = *(const float4*)(wsrc + (seg << 6));
    #pragma unroll
    for (int seg = 0; seg < 8; ++seg) {
        unsigned int p0 = (unsigned int)f2bf(pf[seg].x) | ((unsigned int)f2bf(pf[seg].y) << 16);
        unsigned int p1 = (unsigned int)f2bf(pf[seg].z) | ((unsigned int)f2bf(pf[seg].w) << 16);
        *(uint2*)(wlds + ldsbase + (((seg << 6) + c) ^ swz)) = make_uint2(p0, p1);
    }
    __syncthreads();                      // idx_lds + wlds chunk 0 visible

    int rowoff[4], gswz[4];
    #pragma unroll
    for (int g = 0; g < 4; g++) {
        int v = idx_lds[(g << 7) + bl];
        rowoff[g] = ((g << 4) + v) << 9;
        gswz[g]   = v << 3;
    }

    // ---- prefetch chunk 1 (HBM overlaps chunk-0 compute) ----
    #pragma unroll
    for (int seg = 0; seg < 8; ++seg)
        pf[seg] = *(const float4*)(wsrc + 512 + (seg << 6));

    float acc[4] = {0.f, 0.f, 0.f, 0.f};
    const int qq = q << 6;                // 64-i octant within chunk

    // ---- compute chunk 0 (i 0..511) ----
    #pragma unroll 4
    for (int ii = 0; ii < 64; ii += 8) {
        const int il = qq + ii;
        float l[8];
        #pragma unroll
        for (int u = 0; u < 8; ++u) l[u] = logits[(il + u) * 256 + bc];
        #pragma unroll
        for (int g = 0; g < 4; g++) {
            uint4 wp = *(const uint4*)(wlds + rowoff[g] + (il ^ gswz[g]));
            acc[g] = fmaf(bflo(wp.x), l[0], acc[g]);
            acc[g] = fmaf(bfhi(wp.x), l[1], acc[g]);
            acc[g] = fmaf(bflo(wp.y), l[2], acc[g]);
            acc[g] = fmaf(bfhi(wp.y), l[3], acc[g]);
            acc[g] = fmaf(bflo(wp.z), l[4], acc[g]);
            acc[g] = fmaf(bfhi(wp.z), l[5], acc[g]);
            acc[g] = fmaf(bflo(wp.w), l[6], acc[g]);
            acc[g] = fmaf(bfhi(wp.w), l[7], acc[g]);
        }
    }
    __syncthreads();

    // ---- write chunk 1 ----
    #pragma unroll
    for (int seg = 0; seg < 8; ++seg) {
        unsigned int p0 = (unsigned int)f2bf(pf[seg].x) | ((unsigned int)f2bf(pf[seg].y) << 16);
        unsigned int p1 = (unsigned int)f2bf(pf[seg].z) | ((unsigned int)f2bf(pf[seg].w) << 16);
        *(uint2*)(wlds + ldsbase + (((seg << 6) + c) ^ swz)) = make_uint2(p0, p1);
    }
    __syncthreads();

    // ---- compute chunk 1 (i 512..1023) ----
    #pragma unroll 4
    for (int ii = 0; ii < 64; ii += 8) {
        const int il = qq + ii;
        float l[8];
        #pragma unroll
        for (int u = 0; u < 8; ++u) l[u] = logits[(512 + il + u) * 256 + bc];
        #pragma unroll
        for (int g = 0; g < 4; g++) {
            uint4 wp = *(const uint4*)(wlds + rowoff[g] + (il ^ gswz[g]));
            acc[g] = fmaf(bflo(wp.x), l[0], acc[g]);
            acc[g] = fmaf(bfhi(wp.x), l[1], acc[g]);
            acc[g] = fmaf(bflo(wp.y), l[2], acc[g]);
            acc[g] = fmaf(bfhi(wp.y), l[3], acc[g]);
            acc[g] = fmaf(bflo(wp.z), l[4], acc[g]);
            acc[g] = fmaf(bfhi(wp.z), l[5], acc[g]);
            acc[g] = fmaf(bflo(wp.w), l[6], acc[g]);
            acc[g] = fmaf(bfhi(wp.w), l[7], acc[g]);
        }
    }
    __syncthreads();                      // all gathers done -> red alias valid

    // ---- reduce 8 octants, clip, bias, store out ----
    if (q > 0) {
        #pragma unroll
        for (int g = 0; g < 4; g++) red[((q - 1) * 4 + g) * 128 + bl] = acc[g];
    }
    __syncthreads();
    if (t < 128) {
        #pragma unroll
        for (int g = 0; g < 4; g++) {
            float tot = acc[g];
            #pragma unroll
            for (int p = 0; p < 7; p++) tot += red[(p * 4 + g) * 128 + t];
            float outv = fminf(fmaxf(tot, LO), HI);
            if (s0 + g == 0) outv = bias[0];      // neuron 0 forced to bias
            outp[(s0 + g) * 256 + bc] = outv;
        }
    }
}

// ---------------------------------------------------------------------------
// K2b: coef from (outp, targets, colb) + streaming update
//      new_w = clamp(w - coef*lT[b*], +-5)  (or verbatim copy).
// ---------------------------------------------------------------------------
__global__ __launch_bounds__(256) void k2b_update(
    const float* __restrict__ weights,
    const float* __restrict__ lT,
    const float* __restrict__ outp,
    const float* __restrict__ targets,
    const int*   __restrict__ colb,
    float* __restrict__ outw)
{
    const int t  = threadIdx.x;
    const int r0 = blockIdx.x << 2;
    const int o  = t << 2;
    #pragma unroll
    for (int rr = 0; rr < 4; rr++) {
        const int row = r0 + rr;
        const int col = colb[row];        // uniform across block
        float cf = 0.f;
        if (col >= 0) {
            float ov = outp[(row >> 4) * 256 + col];
            float sg = 1.f / (1.f + __expf(-ov));
            cf = LRC * (sg - targets[col]);
        }
        float4 wv = *(const float4*)(weights + (long)row * 1024 + o);
        float4 res = wv;                  // untouched row: verbatim copy
        if (col >= 0) {
            float4 lv = *(const float4*)(lT + (long)col * 1024 + o);
            res.x = fminf(fmaxf(wv.x - cf * lv.x, -WCLIP), WCLIP);
            res.y = fminf(fmaxf(wv.y - cf * lv.y, -WCLIP), WCLIP);
            res.z = fminf(fmaxf(wv.z - cf * lv.z, -WCLIP), WCLIP);
            res.w = fminf(fmaxf(wv.w - cf * lv.w, -WCLIP), WCLIP);
        }
        *(float4*)(outw + (long)row * 1024 + o) = res;
    }
}

// ---------------------------------------------------------------------------
extern "C" void kernel_launch(void* const* d_in, const int* in_sizes, int n_in,
                              void* d_out, int out_size, void* d_ws, size_t ws_size,
                              hipStream_t stream) {
    const float* logits  = (const float*)d_in[0];   // (1024, 256)
    const float* ctx     = (const float*)d_in[1];   // (512, 256)
    const float* targets = (const float*)d_in[2];   // (256)
    const float* weights = (const float*)d_in[3];   // (1024, 16, 1024)
    const float* cmap    = (const float*)d_in[4];   // (1024, 4, 512)
    const float* cbias   = (const float*)d_in[5];   // (1024, 4, 1)
    const float* bias    = (const float*)d_in[6];   // (1)

    float* outp = (float*)d_out;                    // (1024, 256)
    float* outw = outp + 1024 * 256;                // (1024, 16, 1024)

    char* ws = (char*)d_ws;
    float* lT   = (float*)ws;                       // 1 MB
    int*   colb = (int*)(ws + (1 << 20));           // 64 KB

    // K1 partials: 4 x 4 MB = 16 MB carved from outw (dead until k2b writes;
    // k2a consumes pd before k2b runs — stream-ordered).
    float* pd = outw;

    k1_part   <<<577, 256, 0, stream>>>(cmap, ctx, logits, pd, lT, colb);
    k2a_fwd   <<<512, 1024, 0, stream>>>(logits, weights, bias, cbias, pd,
                                         outp, colb);
    k2b_update<<<4096, 256, 0, stream>>>(weights, lT, outp, targets, colb, outw);
}